// Round 12
// baseline (151.022 us; speedup 1.0000x reference)
//
#include <hip/hip_runtime.h>
#include <hip/hip_bf16.h>

#define B_ 32
#define C_ 1000
#define H_ 512
#define NP 1024   // padded node count (N=1001 real)

typedef __attribute__((ext_vector_type(4))) int i32x4;

__device__ __forceinline__ float tanh_fast(float x) {
  float ax = fminf(fabsf(x), 15.0f);
  float e = __expf(2.0f * ax);
  float t = (e - 1.0f) / (e + 1.0f);
  return copysignf(t, x);
}
__device__ __forceinline__ float sc2f(unsigned v) {   // sext low byte -> float
  return (float)(int)(signed char)v;
}
__device__ __forceinline__ void gload16(const void* g, void* l) {
  __builtin_amdgcn_global_load_lds((const __attribute__((address_space(1))) unsigned*)g,
                                   (__attribute__((address_space(3))) unsigned*)l, 16, 0, 0);
}

// ---------------- K1: normalize -> per-node i8 quant [2][32][1024][512]; zero r ----------------
// Block->mb mapping XCD-pinned: mb&7 == blockIdx%8, matching k_gram's consumer mapping.
__global__ __launch_bounds__(256) void k_norm(const float* __restrict__ it, const float* __restrict__ ii,
                                              const float* __restrict__ bt, const float* __restrict__ bi,
                                              signed char* __restrict__ xq, float* __restrict__ nrm,
                                              float* __restrict__ qs, float* __restrict__ zero_base) {
  int zi = blockIdx.x * 256 + threadIdx.x;
  if (zi < 65536) zero_base[zi] = 0.0f;    // r only (y/go no longer exist/need zeroing)

  int u = blockIdx.x;                       // [0, 16384)
  int w = threadIdx.x >> 6, lane = threadIdx.x & 63;
  int xcd = u & 7, v = u >> 3;              // v in [0, 2048)
  int mb = (v & 7) * 8 + xcd;               // mb&7 == blockIdx%8
  int grp = v >> 3;                         // [0, 256)
  int wid = mb * NP + grp * 4 + w;
  int node = grp * 4 + w;
  int b = mb & 31, mod = mb >> 5;
  const float* src = nullptr;
  if (node == 0) src = (mod ? ii : it) + b * H_;
  else if (node <= C_) src = (mod ? bi : bt) + ((size_t)b * C_ + (node - 1)) * H_;
  float4 v0 = make_float4(0.f, 0.f, 0.f, 0.f), v1 = v0;
  if (src) {
    const float4* s4 = (const float4*)src;
    v0 = s4[lane * 2]; v1 = s4[lane * 2 + 1];
  }
  float ss = v0.x*v0.x + v0.y*v0.y + v0.z*v0.z + v0.w*v0.w
           + v1.x*v1.x + v1.y*v1.y + v1.z*v1.z + v1.w*v1.w;
  #pragma unroll
  for (int o = 32; o; o >>= 1) ss += __shfl_xor(ss, o);
  float n = sqrtf(ss);
  if (lane == 0) nrm[wid] = n;
  float inv = 1.0f / fmaxf(n, 1e-12f);
  float x[8] = {v0.x*inv, v0.y*inv, v0.z*inv, v0.w*inv, v1.x*inv, v1.y*inv, v1.z*inv, v1.w*inv};
  float m8 = 0.f;
  #pragma unroll
  for (int j = 0; j < 8; ++j) m8 = fmaxf(m8, fabsf(x[j]));
  #pragma unroll
  for (int o = 32; o; o >>= 1) m8 = fmaxf(m8, __shfl_xor(m8, o));
  if (lane == 0) qs[wid] = m8 * (1.0f / 127.0f);
  float invq = (m8 > 0.f) ? 127.0f / m8 : 0.f;
  int q[8];
  #pragma unroll
  for (int j = 0; j < 8; ++j) q[j] = __float2int_rn(x[j] * invq);
  unsigned lo = (q[0] & 255) | ((q[1] & 255) << 8) | ((q[2] & 255) << 16) | ((unsigned)(q[3] & 255) << 24);
  unsigned hi = (q[4] & 255) | ((q[5] & 255) << 8) | ((q[6] & 255) << 16) | ((unsigned)(q[7] & 255) << 24);
  *(uint2*)(xq + (size_t)wid * H_ + lane * 8) = make_uint2(lo, hi);
}

// ---------------- K2: i8 Gram row-sums, symmetric ti<=tj. 4-buffer LDS, ONE barrier/K-step ----------------
// Single-barrier safety: a wave's ds_reads of step s-1 retire before its step-(s-1) MFMAs issue
// (register dep), which precede its barrier arrival at step s. So after the rendezvous at step s,
// all waves' step s-1 reads are retired -> staging buf (s+3)%4 (last read at step s-1) is safe.
// Stage->consume gap = 3 steps (~450cy) > L2 latency (~200-300cy).
__global__ __launch_bounds__(256) void k_gram(const signed char* __restrict__ xq,
                                              const float* __restrict__ qs,
                                              float* __restrict__ r, float* __restrict__ sc) {
  __shared__ __align__(16) unsigned char As[4 * 8192];
  __shared__ __align__(16) unsigned char Bs[4 * 8192];
  __shared__ float s_qs[256];
  int orig = blockIdx.x;
  int xcd = orig & 7;                // all 36 tiles of an mb on one XCD -> slice L2-resident
  int k = orig >> 3;
  int mb = xcd + 8 * (k / 36);
  int idx = k % 36;
  int ti = 0, rem = idx;
  while (rem >= 8 - ti) { rem -= 8 - ti; ++ti; }
  int tj = ti + rem;
  bool diag = (ti == tj);
  const signed char* X = xq + (size_t)mb * NP * H_;
  int tid = threadIdx.x;
  int w = tid >> 6, lane = tid & 63;
  int wr = w >> 1, wc = w & 1;

  if (tid < 128) s_qs[tid] = qs[mb * NP + ti * 128 + tid];
  else           s_qs[tid] = qs[mb * NP + tj * 128 + (tid - 128)];

  i32x4 acc[4][4] = {};
  int lrow = lane >> 2;   // row within 16-row staging chunk
  int ps0 = lane & 3;     // physical 16B segment

  auto stage = [&](int buf, int ks) {
    #pragma unroll
    for (int q = 0; q < 2; ++q) {
      int chunk = w * 2 + q;
      int row = chunk * 16 + lrow;
      int qq = ps0 ^ ((row >> 1) & 3);  // logical k-segment at this physical slot
      gload16(X + (size_t)(ti * 128 + row) * H_ + ks * 64 + qq * 16,
              (void*)(As + buf * 8192 + chunk * 1024));
      if (!diag)
        gload16(X + (size_t)(tj * 128 + row) * H_ + ks * 64 + qq * 16,
                (void*)(Bs + buf * 8192 + chunk * 1024));
    }
  };

  auto do_step = [&](const unsigned char* Ab, const unsigned char* Bb) {
    i32x4 af[4], bf[4];
    #pragma unroll
    for (int mi = 0; mi < 4; ++mi) {
      int row = wr * 64 + mi * 16 + (lane & 15);
      int ps = (lane >> 4) ^ ((row >> 1) & 3);
      af[mi] = *(const i32x4*)(Ab + row * 64 + ps * 16);
    }
    #pragma unroll
    for (int ni = 0; ni < 4; ++ni) {
      int row = wc * 64 + ni * 16 + (lane & 15);
      int ps = (lane >> 4) ^ ((row >> 1) & 3);
      bf[ni] = *(const i32x4*)(Bb + row * 64 + ps * 16);
    }
    #pragma unroll
    for (int mi = 0; mi < 4; ++mi)
      #pragma unroll
      for (int ni = 0; ni < 4; ++ni)
        acc[mi][ni] = __builtin_amdgcn_mfma_i32_16x16x64_i8(af[mi], bf[ni], acc[mi][ni], 0, 0, 0);
  };

  stage(0, 0); stage(1, 1); stage(2, 2); stage(3, 3);   // 4 stages in flight
  if (!diag) {                              // 4 loads per stage
    #pragma unroll
    for (int ks = 0; ks < 8; ++ks) {
      if (ks == 0)      asm volatile("s_waitcnt vmcnt(12)" ::: "memory");  // drain stage 0, keep 1-3
      else if (ks < 6)  asm volatile("s_waitcnt vmcnt(8)" ::: "memory");   // drain stage ks, keep 2 ahead
      else if (ks == 6) asm volatile("s_waitcnt vmcnt(4)" ::: "memory");
      else              asm volatile("s_waitcnt vmcnt(0)" ::: "memory");
      __builtin_amdgcn_s_barrier();          // buf ks%4 staged everywhere; step ks-1 reads all retired
      if (ks >= 1 && ks <= 4) stage((ks + 3) & 3, ks + 3);
      do_step(As + (ks & 3) * 8192, Bs + (ks & 3) * 8192);
    }
  } else {                                   // 2 loads per stage
    #pragma unroll
    for (int ks = 0; ks < 8; ++ks) {
      if (ks == 0)      asm volatile("s_waitcnt vmcnt(6)" ::: "memory");
      else if (ks < 6)  asm volatile("s_waitcnt vmcnt(4)" ::: "memory");
      else if (ks == 6) asm volatile("s_waitcnt vmcnt(2)" ::: "memory");
      else              asm volatile("s_waitcnt vmcnt(0)" ::: "memory");
      __builtin_amdgcn_s_barrier();
      if (ks >= 1 && ks <= 4) stage((ks + 3) & 3, ks + 3);
      do_step(As + (ks & 3) * 8192, As + (ks & 3) * 8192);
    }
  }

  __syncthreads();   // s_qs visible (and final drain)
  // epilogue: clip (int), dequant via qs, row/col sums. C/D: col=lane&15, row=(lane>>4)*4+reg
  float* rr = r + mb * NP;
  float qsc[4];
  #pragma unroll
  for (int ni = 0; ni < 4; ++ni) qsc[ni] = s_qs[128 + wc * 64 + ni * 16 + (lane & 15)];
  #pragma unroll
  for (int mi = 0; mi < 4; ++mi) {
    #pragma unroll
    for (int reg = 0; reg < 4; ++reg) {
      float v = 0.f;
      #pragma unroll
      for (int ni = 0; ni < 4; ++ni) {
        int d = acc[mi][ni][reg];
        v += (d > 0 ? (float)d : 0.f) * qsc[ni];
      }
      v += __shfl_xor(v, 1); v += __shfl_xor(v, 2); v += __shfl_xor(v, 4); v += __shfl_xor(v, 8);
      if ((lane & 15) == 0) {
        int rloc = wr * 64 + mi * 16 + (lane >> 4) * 4 + reg;
        atomicAdd(&rr[ti * 128 + rloc], v * s_qs[rloc]);
      }
    }
  }
  if (!diag) {
    #pragma unroll
    for (int ni = 0; ni < 4; ++ni) {
      float s = 0.f;
      #pragma unroll
      for (int mi = 0; mi < 4; ++mi)
        #pragma unroll
        for (int reg = 0; reg < 4; ++reg) {
          int d = acc[mi][ni][reg];
          s += (d > 0 ? (float)d : 0.f) * s_qs[wr * 64 + mi * 16 + (lane >> 4) * 4 + reg];
        }
      s += __shfl_xor(s, 16); s += __shfl_xor(s, 32);
      if (lane < 16) {
        int cloc = wc * 64 + ni * 16 + lane;
        atomicAdd(&rr[tj * 128 + cloc], s * s_qs[128 + cloc]);
      }
    }
  }
  if (ti == 0 && wr == 0 && (lane >> 4) == 0) {
    float q0 = s_qs[0];
    float* scc = sc + mb * NP;
    #pragma unroll
    for (int ni = 0; ni < 4; ++ni) {
      int col = tj * 128 + wc * 64 + ni * 16 + (lane & 15);
      int d = acc[0][ni][0];                    // row 0 of G
      scc[col] = (d > 0 ? (float)d : 0.f) * q0 * qsc[ni];
    }
  }
}

// ---------------- K3: fused y+go. One block per batch b: y_tt,y_it in LDS -> go[b][:] direct ----------------
__global__ __launch_bounds__(512) void k_yg(const signed char* __restrict__ xq,
                                            const float* __restrict__ r, const float* __restrict__ sc,
                                            const float* __restrict__ nrm, const float* __restrict__ qs,
                                            const float* __restrict__ Wtt, const float* __restrict__ btt,
                                            const float* __restrict__ Wit, const float* __restrict__ bit,
                                            float* __restrict__ go) {
  __shared__ float s_w[1024];
  __shared__ __align__(16) float s_part[8][512];
  __shared__ float ym[2][512];
  int b = blockIdx.x;                       // [0,32)
  int t = threadIdx.x;                      // [0,512)
  int w = t >> 6, lane = t & 63;

  for (int mod = 0; mod < 2; ++mod) {
    int mb = mod * 32 + b;
    const float* rr = r + mb * NP;
    __syncthreads();   // prior iteration's s_part reads done before overwrite
    float d0 = rsqrtf(rr[0] + 1.0f);
    #pragma unroll
    for (int m = t; m < 1024; m += 512) {
      float wm = 0.f;
      if (m < 1001) {
        float dm = rsqrtf(rr[m] + 1.0f);
        wm = d0 * dm * (sc[mb * NP + m] + (m == 0 ? 1.0f : 0.0f)) * nrm[mb * NP + m] * qs[mb * NP + m];
      }
      s_w[m] = wm;
    }
    __syncthreads();
    float a[8] = {};
    const signed char* X = xq + (size_t)mb * NP * H_ + (size_t)(w * 128) * H_ + lane * 8;
    #pragma unroll 8
    for (int i = 0; i < 128; ++i) {
      float wm = s_w[w * 128 + i];
      uint2 vv = *(const uint2*)(X + (size_t)i * H_);
      a[0] = fmaf(wm, sc2f(vv.x), a[0]);
      a[1] = fmaf(wm, sc2f(vv.x >> 8), a[1]);
      a[2] = fmaf(wm, sc2f(vv.x >> 16), a[2]);
      a[3] = fmaf(wm, sc2f(vv.x >> 24), a[3]);
      a[4] = fmaf(wm, sc2f(vv.y), a[4]);
      a[5] = fmaf(wm, sc2f(vv.y >> 8), a[5]);
      a[6] = fmaf(wm, sc2f(vv.y >> 16), a[6]);
      a[7] = fmaf(wm, sc2f(vv.y >> 24), a[7]);
    }
    #pragma unroll
    for (int j = 0; j < 8; ++j) s_part[w][lane * 8 + j] = a[j];
    __syncthreads();
    float yv = 0.f;
    #pragma unroll
    for (int ww = 0; ww < 8; ++ww) yv += s_part[ww][t];
    ym[mod][t] = yv;
  }
  __syncthreads();

  // phase B: go[b][k] = 0.7*tanh(y_tt^T Wtt + btt[k]) + 0.3*tanh(y_it^T Wit + bit[k]); k = t
  float att = btt[t], ait = bit[t];
  #pragma unroll 8
  for (int h = 0; h < H_; ++h) {
    att = fmaf(ym[0][h], Wtt[h * H_ + t], att);
    ait = fmaf(ym[1][h], Wit[h * H_ + t], ait);
  }
  go[b * H_ + t] = 0.7f * tanh_fast(att) + 0.3f * tanh_fast(ait);
}

// ---------------- K4: out = 0.5*(nrm*qs*q) + 0.5*graph_o; XCD-pinned mb mapping ----------------
__global__ __launch_bounds__(256) void k_out(const signed char* __restrict__ xq,
                                             const float* __restrict__ nrm, const float* __restrict__ qs,
                                             const float* __restrict__ go, float* __restrict__ out) {
  int u = blockIdx.x;                       // [0,16000)
  int w = threadIdx.x >> 6, lane = threadIdx.x & 63;
  int xcd = u & 7, v = u >> 3;              // v in [0,2000)
  int mbix = v / 250;                       // [0,8)
  int rowgrp = v - mbix * 250;              // [0,250)
  int mb = mbix * 8 + xcd;                  // mb&7 == blockIdx%8
  int mod = mb >> 5, b = mb & 31;
  int c = rowgrp * 4 + w;                   // [0,1000)
  size_t node_off = (size_t)(mb * NP + c + 1);
  float hnq = 0.5f * nrm[node_off] * qs[node_off];
  uint2 x = *(const uint2*)(xq + node_off * H_ + lane * 8);
  const float4* g4 = (const float4*)(go + b * H_ + lane * 8);
  float4 g0 = g4[0], g1 = g4[1];
  float4 o0, o1;
  o0.x = fmaf(hnq, sc2f(x.x), 0.5f * g0.x);
  o0.y = fmaf(hnq, sc2f(x.x >> 8), 0.5f * g0.y);
  o0.z = fmaf(hnq, sc2f(x.x >> 16), 0.5f * g0.z);
  o0.w = fmaf(hnq, sc2f(x.x >> 24), 0.5f * g0.w);
  o1.x = fmaf(hnq, sc2f(x.y), 0.5f * g1.x);
  o1.y = fmaf(hnq, sc2f(x.y >> 8), 0.5f * g1.y);
  o1.z = fmaf(hnq, sc2f(x.y >> 16), 0.5f * g1.z);
  o1.w = fmaf(hnq, sc2f(x.y >> 24), 0.5f * g1.w);
  size_t orow = (size_t)(mod * 32000 + b * 1000 + c);
  float4* o4 = (float4*)(out + orow * H_ + lane * 8);
  o4[0] = o0; o4[1] = o1;
}

extern "C" void kernel_launch(void* const* d_in, const int* in_sizes, int n_in,
                              void* d_out, int out_size, void* d_ws, size_t ws_size,
                              hipStream_t stream) {
  const float* it  = (const float*)d_in[0];
  const float* ii  = (const float*)d_in[1];
  const float* bt  = (const float*)d_in[2];
  const float* bi  = (const float*)d_in[3];
  const float* Wtt = (const float*)d_in[4];
  const float* btt = (const float*)d_in[5];
  const float* Wit = (const float*)d_in[6];
  const float* bit = (const float*)d_in[7];

  char* ws = (char*)d_ws;
  signed char* xq = (signed char*)ws;                             // 2*32*1024*512 i8 = 33,554,432 B
  size_t off = 33554432;
  float* nrm = (float*)(ws + off); off += 262144;                 // [2][32][1024] f32
  float* qs  = (float*)(ws + off); off += 262144;
  float* sc  = (float*)(ws + off); off += 262144;
  float* r   = (float*)(ws + off); off += 262144;                 // zeroed in k_norm
  float* go  = (float*)(ws + off); off += 65536;                  // fully written by k_yg

  k_norm<<<16384, 256, 0, stream>>>(it, ii, bt, bi, xq, nrm, qs, r);
  k_gram<<<64 * 36, 256, 0, stream>>>(xq, qs, r, sc);
  k_yg<<<32, 512, 0, stream>>>(xq, r, sc, nrm, qs, Wtt, btt, Wit, bit, go);
  k_out<<<16000, 256, 0, stream>>>(xq, nrm, qs, go, (float*)d_out);
}

// Round 13
// 131.285 us; speedup vs baseline: 1.1503x; 1.1503x over previous
//
#include <hip/hip_runtime.h>
#include <hip/hip_bf16.h>

#define B_ 32
#define C_ 1000
#define H_ 512
#define NP 1024   // padded node count (N=1001 real)

typedef __attribute__((ext_vector_type(4))) int i32x4;

__device__ __forceinline__ float tanh_fast(float x) {
  float ax = fminf(fabsf(x), 15.0f);
  float e = __expf(2.0f * ax);
  float t = (e - 1.0f) / (e + 1.0f);
  return copysignf(t, x);
}
__device__ __forceinline__ float sc2f(unsigned v) {   // sext low byte -> float
  return (float)(int)(signed char)v;
}
__device__ __forceinline__ void gload16(const void* g, void* l) {
  __builtin_amdgcn_global_load_lds((const __attribute__((address_space(1))) unsigned*)g,
                                   (__attribute__((address_space(3))) unsigned*)l, 16, 0, 0);
}

// ---------------- K1: normalize -> per-node i8 quant [2][32][1024][512]; zero r+y ----------------
// Block->mb mapping XCD-pinned: mb&7 == blockIdx%8, matching k_gram's consumer mapping.
__global__ __launch_bounds__(256) void k_norm(const float* __restrict__ it, const float* __restrict__ ii,
                                              const float* __restrict__ bt, const float* __restrict__ bi,
                                              signed char* __restrict__ xq, float* __restrict__ nrm,
                                              float* __restrict__ qs, float* __restrict__ zero_base) {
  int zi = blockIdx.x * 256 + threadIdx.x;
  if (zi < 98304) zero_base[zi] = 0.0f;    // r (65536) + y (32768) contiguous

  int u = blockIdx.x;                       // [0, 16384)
  int w = threadIdx.x >> 6, lane = threadIdx.x & 63;
  int xcd = u & 7, v = u >> 3;              // v in [0, 2048)
  int mb = (v & 7) * 8 + xcd;               // mb&7 == blockIdx%8
  int grp = v >> 3;                         // [0, 256)
  int wid = mb * NP + grp * 4 + w;
  int node = grp * 4 + w;
  int b = mb & 31, mod = mb >> 5;
  const float* src = nullptr;
  if (node == 0) src = (mod ? ii : it) + b * H_;
  else if (node <= C_) src = (mod ? bi : bt) + ((size_t)b * C_ + (node - 1)) * H_;
  float4 v0 = make_float4(0.f, 0.f, 0.f, 0.f), v1 = v0;
  if (src) {
    const float4* s4 = (const float4*)src;
    v0 = s4[lane * 2]; v1 = s4[lane * 2 + 1];
  }
  float ss = v0.x*v0.x + v0.y*v0.y + v0.z*v0.z + v0.w*v0.w
           + v1.x*v1.x + v1.y*v1.y + v1.z*v1.z + v1.w*v1.w;
  #pragma unroll
  for (int o = 32; o; o >>= 1) ss += __shfl_xor(ss, o);
  float n = sqrtf(ss);
  if (lane == 0) nrm[wid] = n;
  float inv = 1.0f / fmaxf(n, 1e-12f);
  float x[8] = {v0.x*inv, v0.y*inv, v0.z*inv, v0.w*inv, v1.x*inv, v1.y*inv, v1.z*inv, v1.w*inv};
  float m8 = 0.f;
  #pragma unroll
  for (int j = 0; j < 8; ++j) m8 = fmaxf(m8, fabsf(x[j]));
  #pragma unroll
  for (int o = 32; o; o >>= 1) m8 = fmaxf(m8, __shfl_xor(m8, o));
  if (lane == 0) qs[wid] = m8 * (1.0f / 127.0f);
  float invq = (m8 > 0.f) ? 127.0f / m8 : 0.f;
  int q[8];
  #pragma unroll
  for (int j = 0; j < 8; ++j) q[j] = __float2int_rn(x[j] * invq);
  unsigned lo = (q[0] & 255) | ((q[1] & 255) << 8) | ((q[2] & 255) << 16) | ((unsigned)(q[3] & 255) << 24);
  unsigned hi = (q[4] & 255) | ((q[5] & 255) << 8) | ((q[6] & 255) << 16) | ((unsigned)(q[7] & 255) << 24);
  *(uint2*)(xq + (size_t)wid * H_ + lane * 8) = make_uint2(lo, hi);
}

// ---------------- K2: i8 Gram row-sums, symmetric ti<=tj. 3-buffer LDS, ONE barrier/K-step ----------------
// (r11-proven: 3 buffers keeps 3 blocks/CU; r12's 4-buffer dropped to 2 blocks/CU and regressed.)
__global__ __launch_bounds__(256) void k_gram(const signed char* __restrict__ xq,
                                              const float* __restrict__ qs,
                                              float* __restrict__ r, float* __restrict__ sc) {
  __shared__ __align__(16) unsigned char As[3 * 8192];
  __shared__ __align__(16) unsigned char Bs[3 * 8192];
  __shared__ float s_qs[256];
  int orig = blockIdx.x;
  int xcd = orig & 7;                // all 36 tiles of an mb on one XCD -> slice L2-resident
  int k = orig >> 3;
  int mb = xcd + 8 * (k / 36);
  int idx = k % 36;
  int ti = 0, rem = idx;
  while (rem >= 8 - ti) { rem -= 8 - ti; ++ti; }
  int tj = ti + rem;
  bool diag = (ti == tj);
  const signed char* X = xq + (size_t)mb * NP * H_;
  int tid = threadIdx.x;
  int w = tid >> 6, lane = tid & 63;
  int wr = w >> 1, wc = w & 1;

  if (tid < 128) s_qs[tid] = qs[mb * NP + ti * 128 + tid];
  else           s_qs[tid] = qs[mb * NP + tj * 128 + (tid - 128)];

  i32x4 acc[4][4] = {};
  int lrow = lane >> 2;   // row within 16-row staging chunk
  int ps0 = lane & 3;     // physical 16B segment

  auto stage = [&](int buf, int ks) {
    #pragma unroll
    for (int q = 0; q < 2; ++q) {
      int chunk = w * 2 + q;
      int row = chunk * 16 + lrow;
      int qq = ps0 ^ ((row >> 1) & 3);  // logical k-segment at this physical slot
      gload16(X + (size_t)(ti * 128 + row) * H_ + ks * 64 + qq * 16,
              (void*)(As + buf * 8192 + chunk * 1024));
      if (!diag)
        gload16(X + (size_t)(tj * 128 + row) * H_ + ks * 64 + qq * 16,
                (void*)(Bs + buf * 8192 + chunk * 1024));
    }
  };

  auto do_step = [&](const unsigned char* Ab, const unsigned char* Bb) {
    i32x4 af[4], bf[4];
    #pragma unroll
    for (int mi = 0; mi < 4; ++mi) {
      int row = wr * 64 + mi * 16 + (lane & 15);
      int ps = (lane >> 4) ^ ((row >> 1) & 3);
      af[mi] = *(const i32x4*)(Ab + row * 64 + ps * 16);
    }
    #pragma unroll
    for (int ni = 0; ni < 4; ++ni) {
      int row = wc * 64 + ni * 16 + (lane & 15);
      int ps = (lane >> 4) ^ ((row >> 1) & 3);
      bf[ni] = *(const i32x4*)(Bb + row * 64 + ps * 16);
    }
    #pragma unroll
    for (int mi = 0; mi < 4; ++mi)
      #pragma unroll
      for (int ni = 0; ni < 4; ++ni)
        acc[mi][ni] = __builtin_amdgcn_mfma_i32_16x16x64_i8(af[mi], bf[ni], acc[mi][ni], 0, 0, 0);
  };

  stage(0, 0); stage(1, 1); stage(2, 2);   // 3 stages in flight
  if (!diag) {                              // 4 loads per stage
    #pragma unroll
    for (int ks = 0; ks < 8; ++ks) {
      if (ks == 0)      asm volatile("s_waitcnt vmcnt(8)" ::: "memory");   // drain stage 0, keep 1,2
      else if (ks < 7)  asm volatile("s_waitcnt vmcnt(4)" ::: "memory");   // drain stage ks, keep ks+1
      else              asm volatile("s_waitcnt vmcnt(0)" ::: "memory");
      __builtin_amdgcn_s_barrier();          // buf ks%3 staged everywhere; step ks-1 reads all retired
      if (ks >= 1 && ks <= 5) stage((ks + 2) % 3, ks + 2);
      do_step(As + (ks % 3) * 8192, Bs + (ks % 3) * 8192);
    }
  } else {                                   // 2 loads per stage
    #pragma unroll
    for (int ks = 0; ks < 8; ++ks) {
      if (ks == 0)      asm volatile("s_waitcnt vmcnt(4)" ::: "memory");
      else if (ks < 7)  asm volatile("s_waitcnt vmcnt(2)" ::: "memory");
      else              asm volatile("s_waitcnt vmcnt(0)" ::: "memory");
      __builtin_amdgcn_s_barrier();
      if (ks >= 1 && ks <= 5) stage((ks + 2) % 3, ks + 2);
      do_step(As + (ks % 3) * 8192, As + (ks % 3) * 8192);
    }
  }

  __syncthreads();   // s_qs visible (and final drain)
  // epilogue: clip (int), dequant via qs, row/col sums. C/D: col=lane&15, row=(lane>>4)*4+reg
  float* rr = r + mb * NP;
  float qsc[4];
  #pragma unroll
  for (int ni = 0; ni < 4; ++ni) qsc[ni] = s_qs[128 + wc * 64 + ni * 16 + (lane & 15)];
  #pragma unroll
  for (int mi = 0; mi < 4; ++mi) {
    #pragma unroll
    for (int reg = 0; reg < 4; ++reg) {
      float v = 0.f;
      #pragma unroll
      for (int ni = 0; ni < 4; ++ni) {
        int d = acc[mi][ni][reg];
        v += (d > 0 ? (float)d : 0.f) * qsc[ni];
      }
      v += __shfl_xor(v, 1); v += __shfl_xor(v, 2); v += __shfl_xor(v, 4); v += __shfl_xor(v, 8);
      if ((lane & 15) == 0) {
        int rloc = wr * 64 + mi * 16 + (lane >> 4) * 4 + reg;
        atomicAdd(&rr[ti * 128 + rloc], v * s_qs[rloc]);
      }
    }
  }
  if (!diag) {
    #pragma unroll
    for (int ni = 0; ni < 4; ++ni) {
      float s = 0.f;
      #pragma unroll
      for (int mi = 0; mi < 4; ++mi)
        #pragma unroll
        for (int reg = 0; reg < 4; ++reg) {
          int d = acc[mi][ni][reg];
          s += (d > 0 ? (float)d : 0.f) * s_qs[wr * 64 + mi * 16 + (lane >> 4) * 4 + reg];
        }
      s += __shfl_xor(s, 16); s += __shfl_xor(s, 32);
      if (lane < 16) {
        int cloc = wc * 64 + ni * 16 + lane;
        atomicAdd(&rr[tj * 128 + cloc], s * s_qs[128 + cloc]);
      }
    }
  }
  if (ti == 0 && wr == 0 && (lane >> 4) == 0) {
    float q0 = s_qs[0];
    float* scc = sc + mb * NP;
    #pragma unroll
    for (int ni = 0; ni < 4; ++ni) {
      int col = tj * 128 + wc * 64 + ni * 16 + (lane & 15);
      int d = acc[0][ni][0];                    // row 0 of G
      scc[col] = (d > 0 ? (float)d : 0.f) * q0 * qsc[ni];
    }
  }
}

// ---------------- K3: y[mb][h] = sum_m w[m] * q[mb][m][h]; XCD-pinned mb mapping ----------------
__global__ __launch_bounds__(256) void k_y(const signed char* __restrict__ xq,
                                           const float* __restrict__ r, const float* __restrict__ sc,
                                           const float* __restrict__ nrm, const float* __restrict__ qs,
                                           float* __restrict__ y) {
  __shared__ float s_w[128];
  __shared__ __align__(16) float s_part[4][512];
  int bid = blockIdx.x;                     // [0,512)
  int xcd = bid & 7, v = bid >> 3;          // v in [0,64)
  int mb = (v & 7) * 8 + xcd;               // mb&7 == blockIdx%8 (matches producer)
  int chunk = v >> 3;                       // [0,8)
  int m0 = chunk * 128;
  int t = threadIdx.x;
  const float* rr = r + mb * NP;
  if (t < 128) {
    int m = m0 + t;
    float wm = 0.f;
    if (m < 1001) {
      float d0 = rsqrtf(rr[0] + 1.0f);
      float dm = rsqrtf(rr[m] + 1.0f);
      wm = d0 * dm * (sc[mb * NP + m] + (m == 0 ? 1.0f : 0.0f)) * nrm[mb * NP + m] * qs[mb * NP + m];
    }
    s_w[t] = wm;
  }
  __syncthreads();
  int w = t >> 6, lane = t & 63;
  float a[8] = {};
  const signed char* X = xq + (size_t)mb * NP * H_ + lane * 8;
  for (int i = 0; i < 32; ++i) {
    int m = w * 32 + i;
    float wm = s_w[m];
    uint2 vv = *(const uint2*)(X + (size_t)(m0 + m) * H_);
    a[0] = fmaf(wm, sc2f(vv.x), a[0]);
    a[1] = fmaf(wm, sc2f(vv.x >> 8), a[1]);
    a[2] = fmaf(wm, sc2f(vv.x >> 16), a[2]);
    a[3] = fmaf(wm, sc2f(vv.x >> 24), a[3]);
    a[4] = fmaf(wm, sc2f(vv.y), a[4]);
    a[5] = fmaf(wm, sc2f(vv.y >> 8), a[5]);
    a[6] = fmaf(wm, sc2f(vv.y >> 16), a[6]);
    a[7] = fmaf(wm, sc2f(vv.y >> 24), a[7]);
  }
  #pragma unroll
  for (int j = 0; j < 8; ++j) s_part[w][lane * 8 + j] = a[j];
  __syncthreads();
  float v0 = s_part[0][t] + s_part[1][t] + s_part[2][t] + s_part[3][t];
  float v1 = s_part[0][t + 256] + s_part[1][t + 256] + s_part[2][t + 256] + s_part[3][t + 256];
  atomicAdd(&y[mb * H_ + t], v0);
  atomicAdd(&y[mb * H_ + t + 256], v1);
}

// ---------------- K4: go[b][k] = 0.7*tanh(y_tt^T Wtt + btt[k]) + 0.3*tanh(y_it^T Wit + bit[k]) ----------------
// Both modalities per thread (2 independent FMA chains, ILP 2); direct write, no atomics, no zeroing.
__global__ __launch_bounds__(128) void k_go(const float* __restrict__ y,
                                            const float* __restrict__ Wtt, const float* __restrict__ btt,
                                            const float* __restrict__ Wit, const float* __restrict__ bit,
                                            float* __restrict__ go) {
  int bid = blockIdx.x;          // 0..127: (quarter, b)
  int b = bid & 31, quarter = bid >> 5;
  int k = quarter * 128 + threadIdx.x;
  const float* ytt = y + b * H_;
  const float* yit = y + (32 + b) * H_;
  float att = btt[k], ait = bit[k];
  #pragma unroll 8
  for (int h = 0; h < H_; ++h) {
    att = fmaf(ytt[h], Wtt[h * H_ + k], att);
    ait = fmaf(yit[h], Wit[h * H_ + k], ait);
  }
  go[b * H_ + k] = 0.7f * tanh_fast(att) + 0.3f * tanh_fast(ait);
}

// ---------------- K5: out = 0.5*(nrm*qs*q) + 0.5*graph_o; XCD-pinned mb mapping ----------------
__global__ __launch_bounds__(256) void k_out(const signed char* __restrict__ xq,
                                             const float* __restrict__ nrm, const float* __restrict__ qs,
                                             const float* __restrict__ go, float* __restrict__ out) {
  int u = blockIdx.x;                       // [0,16000)
  int w = threadIdx.x >> 6, lane = threadIdx.x & 63;
  int xcd = u & 7, v = u >> 3;              // v in [0,2000)
  int mbix = v / 250;                       // [0,8)
  int rowgrp = v - mbix * 250;              // [0,250)
  int mb = mbix * 8 + xcd;                  // mb&7 == blockIdx%8
  int mod = mb >> 5, b = mb & 31;
  int c = rowgrp * 4 + w;                   // [0,1000)
  size_t node_off = (size_t)(mb * NP + c + 1);
  float hnq = 0.5f * nrm[node_off] * qs[node_off];
  uint2 x = *(const uint2*)(xq + node_off * H_ + lane * 8);
  const float4* g4 = (const float4*)(go + b * H_ + lane * 8);
  float4 g0 = g4[0], g1 = g4[1];
  float4 o0, o1;
  o0.x = fmaf(hnq, sc2f(x.x), 0.5f * g0.x);
  o0.y = fmaf(hnq, sc2f(x.x >> 8), 0.5f * g0.y);
  o0.z = fmaf(hnq, sc2f(x.x >> 16), 0.5f * g0.z);
  o0.w = fmaf(hnq, sc2f(x.x >> 24), 0.5f * g0.w);
  o1.x = fmaf(hnq, sc2f(x.y), 0.5f * g1.x);
  o1.y = fmaf(hnq, sc2f(x.y >> 8), 0.5f * g1.y);
  o1.z = fmaf(hnq, sc2f(x.y >> 16), 0.5f * g1.z);
  o1.w = fmaf(hnq, sc2f(x.y >> 24), 0.5f * g1.w);
  size_t orow = (size_t)(mod * 32000 + b * 1000 + c);
  float4* o4 = (float4*)(out + orow * H_ + lane * 8);
  o4[0] = o0; o4[1] = o1;
}

extern "C" void kernel_launch(void* const* d_in, const int* in_sizes, int n_in,
                              void* d_out, int out_size, void* d_ws, size_t ws_size,
                              hipStream_t stream) {
  const float* it  = (const float*)d_in[0];
  const float* ii  = (const float*)d_in[1];
  const float* bt  = (const float*)d_in[2];
  const float* bi  = (const float*)d_in[3];
  const float* Wtt = (const float*)d_in[4];
  const float* btt = (const float*)d_in[5];
  const float* Wit = (const float*)d_in[6];
  const float* bit = (const float*)d_in[7];

  char* ws = (char*)d_ws;
  signed char* xq = (signed char*)ws;                             // 2*32*1024*512 i8 = 33,554,432 B
  size_t off = 33554432;
  float* nrm = (float*)(ws + off); off += 262144;                 // [2][32][1024] f32
  float* qs  = (float*)(ws + off); off += 262144;
  float* sc  = (float*)(ws + off); off += 262144;
  float* r   = (float*)(ws + off); off += 262144;                 // zeroed in k_norm
  float* y   = (float*)(ws + off); off += 131072;                 // zeroed in k_norm (contiguous with r)
  float* go  = (float*)(ws + off); off += 65536;                  // fully written by k_go

  k_norm<<<16384, 256, 0, stream>>>(it, ii, bt, bi, xq, nrm, qs, r);
  k_gram<<<64 * 36, 256, 0, stream>>>(xq, qs, r, sc);
  k_y<<<512, 256, 0, stream>>>(xq, r, sc, nrm, qs, y);
  k_go<<<128, 128, 0, stream>>>(y, Wtt, btt, Wit, bit, go);
  k_out<<<16000, 256, 0, stream>>>(xq, nrm, qs, go, (float*)d_out);
}

// Round 14
// 127.515 us; speedup vs baseline: 1.1843x; 1.0296x over previous
//
#include <hip/hip_runtime.h>
#include <hip/hip_bf16.h>

#define B_ 32
#define C_ 1000
#define H_ 512
#define NP 1024   // padded node count (N=1001 real)

typedef __attribute__((ext_vector_type(4))) int i32x4;

__device__ __forceinline__ float tanh_fast(float x) {
  float ax = fminf(fabsf(x), 15.0f);
  float e = __expf(2.0f * ax);
  float t = (e - 1.0f) / (e + 1.0f);
  return copysignf(t, x);
}
__device__ __forceinline__ float sc2f(unsigned v) {   // sext low byte -> float
  return (float)(int)(signed char)v;
}
__device__ __forceinline__ void gload16(const void* g, void* l) {
  __builtin_amdgcn_global_load_lds((const __attribute__((address_space(1))) unsigned*)g,
                                   (__attribute__((address_space(3))) unsigned*)l, 16, 0, 0);
}

// ---------------- K1: normalize -> per-node i8 quant [2][32][1024][512]; zero r/y/go ----------------
// Block->mb mapping XCD-pinned: mb&7 == blockIdx%8, matching k_gram's consumer mapping.
__global__ __launch_bounds__(256) void k_norm(const float* __restrict__ it, const float* __restrict__ ii,
                                              const float* __restrict__ bt, const float* __restrict__ bi,
                                              signed char* __restrict__ xq, float* __restrict__ nrm,
                                              float* __restrict__ qs, float* __restrict__ zero_base) {
  int zi = blockIdx.x * 256 + threadIdx.x;
  if (zi < 114688) zero_base[zi] = 0.0f;   // r + y + go contiguous

  int u = blockIdx.x;                       // [0, 16384)
  int w = threadIdx.x >> 6, lane = threadIdx.x & 63;
  int xcd = u & 7, v = u >> 3;              // v in [0, 2048)
  int mb = (v & 7) * 8 + xcd;               // mb&7 == blockIdx%8
  int grp = v >> 3;                         // [0, 256)
  int wid = mb * NP + grp * 4 + w;
  int node = grp * 4 + w;
  int b = mb & 31, mod = mb >> 5;
  const float* src = nullptr;
  if (node == 0) src = (mod ? ii : it) + b * H_;
  else if (node <= C_) src = (mod ? bi : bt) + ((size_t)b * C_ + (node - 1)) * H_;
  float4 v0 = make_float4(0.f, 0.f, 0.f, 0.f), v1 = v0;
  if (src) {
    const float4* s4 = (const float4*)src;
    v0 = s4[lane * 2]; v1 = s4[lane * 2 + 1];
  }
  float ss = v0.x*v0.x + v0.y*v0.y + v0.z*v0.z + v0.w*v0.w
           + v1.x*v1.x + v1.y*v1.y + v1.z*v1.z + v1.w*v1.w;
  #pragma unroll
  for (int o = 32; o; o >>= 1) ss += __shfl_xor(ss, o);
  float n = sqrtf(ss);
  if (lane == 0) nrm[wid] = n;
  float inv = 1.0f / fmaxf(n, 1e-12f);
  float x[8] = {v0.x*inv, v0.y*inv, v0.z*inv, v0.w*inv, v1.x*inv, v1.y*inv, v1.z*inv, v1.w*inv};
  float m8 = 0.f;
  #pragma unroll
  for (int j = 0; j < 8; ++j) m8 = fmaxf(m8, fabsf(x[j]));
  #pragma unroll
  for (int o = 32; o; o >>= 1) m8 = fmaxf(m8, __shfl_xor(m8, o));
  if (lane == 0) qs[wid] = m8 * (1.0f / 127.0f);
  float invq = (m8 > 0.f) ? 127.0f / m8 : 0.f;
  int q[8];
  #pragma unroll
  for (int j = 0; j < 8; ++j) q[j] = __float2int_rn(x[j] * invq);
  unsigned lo = (q[0] & 255) | ((q[1] & 255) << 8) | ((q[2] & 255) << 16) | ((unsigned)(q[3] & 255) << 24);
  unsigned hi = (q[4] & 255) | ((q[5] & 255) << 8) | ((q[6] & 255) << 16) | ((unsigned)(q[7] & 255) << 24);
  *(uint2*)(xq + (size_t)wid * H_ + lane * 8) = make_uint2(lo, hi);
}

// ---------------- K2: i8 Gram row-sums, symmetric ti<=tj. 3-buffer LDS, ONE barrier/K-step ----------------
// Single-barrier safety: a wave's ds_reads of step s-1 retire before its step-(s-1) MFMAs issue
// (register dep), which precede its barrier arrival at step s. So after the rendezvous at step s,
// all waves' step s-1 reads are retired -> staging buf (s+2)%3 (last read at step s-1) is safe.
__global__ __launch_bounds__(256) void k_gram(const signed char* __restrict__ xq,
                                              const float* __restrict__ qs,
                                              float* __restrict__ r, float* __restrict__ sc) {
  __shared__ __align__(16) unsigned char As[3 * 8192];
  __shared__ __align__(16) unsigned char Bs[3 * 8192];
  __shared__ float s_qs[256];
  int orig = blockIdx.x;
  int xcd = orig & 7;                // all 36 tiles of an mb on one XCD -> slice L2-resident
  int k = orig >> 3;
  int mb = xcd + 8 * (k / 36);
  int idx = k % 36;
  int ti = 0, rem = idx;
  while (rem >= 8 - ti) { rem -= 8 - ti; ++ti; }
  int tj = ti + rem;
  bool diag = (ti == tj);
  const signed char* X = xq + (size_t)mb * NP * H_;
  int tid = threadIdx.x;
  int w = tid >> 6, lane = tid & 63;
  int wr = w >> 1, wc = w & 1;

  if (tid < 128) s_qs[tid] = qs[mb * NP + ti * 128 + tid];
  else           s_qs[tid] = qs[mb * NP + tj * 128 + (tid - 128)];

  i32x4 acc[4][4] = {};
  int lrow = lane >> 2;   // row within 16-row staging chunk
  int ps0 = lane & 3;     // physical 16B segment

  auto stage = [&](int buf, int ks) {
    #pragma unroll
    for (int q = 0; q < 2; ++q) {
      int chunk = w * 2 + q;
      int row = chunk * 16 + lrow;
      int qq = ps0 ^ ((row >> 1) & 3);  // logical k-segment at this physical slot
      gload16(X + (size_t)(ti * 128 + row) * H_ + ks * 64 + qq * 16,
              (void*)(As + buf * 8192 + chunk * 1024));
      if (!diag)
        gload16(X + (size_t)(tj * 128 + row) * H_ + ks * 64 + qq * 16,
                (void*)(Bs + buf * 8192 + chunk * 1024));
    }
  };

  auto do_step = [&](const unsigned char* Ab, const unsigned char* Bb) {
    i32x4 af[4], bf[4];
    #pragma unroll
    for (int mi = 0; mi < 4; ++mi) {
      int row = wr * 64 + mi * 16 + (lane & 15);
      int ps = (lane >> 4) ^ ((row >> 1) & 3);
      af[mi] = *(const i32x4*)(Ab + row * 64 + ps * 16);
    }
    #pragma unroll
    for (int ni = 0; ni < 4; ++ni) {
      int row = wc * 64 + ni * 16 + (lane & 15);
      int ps = (lane >> 4) ^ ((row >> 1) & 3);
      bf[ni] = *(const i32x4*)(Bb + row * 64 + ps * 16);
    }
    #pragma unroll
    for (int mi = 0; mi < 4; ++mi)
      #pragma unroll
      for (int ni = 0; ni < 4; ++ni)
        acc[mi][ni] = __builtin_amdgcn_mfma_i32_16x16x64_i8(af[mi], bf[ni], acc[mi][ni], 0, 0, 0);
  };

  stage(0, 0); stage(1, 1); stage(2, 2);   // 3 stages in flight
  if (!diag) {                              // 4 loads per stage
    #pragma unroll
    for (int ks = 0; ks < 8; ++ks) {
      if (ks == 0)      asm volatile("s_waitcnt vmcnt(8)" ::: "memory");   // drain stage 0, keep 1,2
      else if (ks < 7)  asm volatile("s_waitcnt vmcnt(4)" ::: "memory");   // drain stage ks, keep ks+1
      else              asm volatile("s_waitcnt vmcnt(0)" ::: "memory");
      __builtin_amdgcn_s_barrier();          // buf ks%3 staged everywhere; step ks-1 reads all retired
      if (ks >= 1 && ks <= 5) stage((ks + 2) % 3, ks + 2);
      do_step(As + (ks % 3) * 8192, Bs + (ks % 3) * 8192);
    }
  } else {                                   // 2 loads per stage
    #pragma unroll
    for (int ks = 0; ks < 8; ++ks) {
      if (ks == 0)      asm volatile("s_waitcnt vmcnt(4)" ::: "memory");
      else if (ks < 7)  asm volatile("s_waitcnt vmcnt(2)" ::: "memory");
      else              asm volatile("s_waitcnt vmcnt(0)" ::: "memory");
      __builtin_amdgcn_s_barrier();
      if (ks >= 1 && ks <= 5) stage((ks + 2) % 3, ks + 2);
      do_step(As + (ks % 3) * 8192, As + (ks % 3) * 8192);
    }
  }

  __syncthreads();   // s_qs visible (and final drain)
  // epilogue: clip (int), dequant via qs, row/col sums. C/D: col=lane&15, row=(lane>>4)*4+reg
  float* rr = r + mb * NP;
  float qsc[4];
  #pragma unroll
  for (int ni = 0; ni < 4; ++ni) qsc[ni] = s_qs[128 + wc * 64 + ni * 16 + (lane & 15)];
  #pragma unroll
  for (int mi = 0; mi < 4; ++mi) {
    #pragma unroll
    for (int reg = 0; reg < 4; ++reg) {
      float v = 0.f;
      #pragma unroll
      for (int ni = 0; ni < 4; ++ni) {
        int d = acc[mi][ni][reg];
        v += (d > 0 ? (float)d : 0.f) * qsc[ni];
      }
      v += __shfl_xor(v, 1); v += __shfl_xor(v, 2); v += __shfl_xor(v, 4); v += __shfl_xor(v, 8);
      if ((lane & 15) == 0) {
        int rloc = wr * 64 + mi * 16 + (lane >> 4) * 4 + reg;
        atomicAdd(&rr[ti * 128 + rloc], v * s_qs[rloc]);
      }
    }
  }
  if (!diag) {
    #pragma unroll
    for (int ni = 0; ni < 4; ++ni) {
      float s = 0.f;
      #pragma unroll
      for (int mi = 0; mi < 4; ++mi)
        #pragma unroll
        for (int reg = 0; reg < 4; ++reg) {
          int d = acc[mi][ni][reg];
          s += (d > 0 ? (float)d : 0.f) * s_qs[wr * 64 + mi * 16 + (lane >> 4) * 4 + reg];
        }
      s += __shfl_xor(s, 16); s += __shfl_xor(s, 32);
      if (lane < 16) {
        int cloc = wc * 64 + ni * 16 + lane;
        atomicAdd(&rr[tj * 128 + cloc], s * s_qs[128 + cloc]);
      }
    }
  }
  if (ti == 0 && wr == 0 && (lane >> 4) == 0) {
    float q0 = s_qs[0];
    float* scc = sc + mb * NP;
    #pragma unroll
    for (int ni = 0; ni < 4; ++ni) {
      int col = tj * 128 + wc * 64 + ni * 16 + (lane & 15);
      int d = acc[0][ni][0];                    // row 0 of G
      scc[col] = (d > 0 ? (float)d : 0.f) * q0 * qsc[ni];
    }
  }
}

// ---------------- K3: y[mb][h] = sum_m w[m] * q[mb][m][h]; XCD-pinned mb mapping ----------------
__global__ __launch_bounds__(256) void k_y(const signed char* __restrict__ xq,
                                           const float* __restrict__ r, const float* __restrict__ sc,
                                           const float* __restrict__ nrm, const float* __restrict__ qs,
                                           float* __restrict__ y) {
  __shared__ float s_w[128];
  __shared__ __align__(16) float s_part[4][512];
  int bid = blockIdx.x;                     // [0,512)
  int xcd = bid & 7, v = bid >> 3;          // v in [0,64)
  int mb = (v & 7) * 8 + xcd;               // mb&7 == blockIdx%8 (matches producer)
  int chunk = v >> 3;                       // [0,8)
  int m0 = chunk * 128;
  int t = threadIdx.x;
  const float* rr = r + mb * NP;
  if (t < 128) {
    int m = m0 + t;
    float wm = 0.f;
    if (m < 1001) {
      float d0 = rsqrtf(rr[0] + 1.0f);
      float dm = rsqrtf(rr[m] + 1.0f);
      wm = d0 * dm * (sc[mb * NP + m] + (m == 0 ? 1.0f : 0.0f)) * nrm[mb * NP + m] * qs[mb * NP + m];
    }
    s_w[t] = wm;
  }
  __syncthreads();
  int w = t >> 6, lane = t & 63;
  float a[8] = {};
  const signed char* X = xq + (size_t)mb * NP * H_ + lane * 8;
  for (int i = 0; i < 32; ++i) {
    int m = w * 32 + i;
    float wm = s_w[m];
    uint2 vv = *(const uint2*)(X + (size_t)(m0 + m) * H_);
    a[0] = fmaf(wm, sc2f(vv.x), a[0]);
    a[1] = fmaf(wm, sc2f(vv.x >> 8), a[1]);
    a[2] = fmaf(wm, sc2f(vv.x >> 16), a[2]);
    a[3] = fmaf(wm, sc2f(vv.x >> 24), a[3]);
    a[4] = fmaf(wm, sc2f(vv.y), a[4]);
    a[5] = fmaf(wm, sc2f(vv.y >> 8), a[5]);
    a[6] = fmaf(wm, sc2f(vv.y >> 16), a[6]);
    a[7] = fmaf(wm, sc2f(vv.y >> 24), a[7]);
  }
  #pragma unroll
  for (int j = 0; j < 8; ++j) s_part[w][lane * 8 + j] = a[j];
  __syncthreads();
  float v0 = s_part[0][t] + s_part[1][t] + s_part[2][t] + s_part[3][t];
  float v1 = s_part[0][t + 256] + s_part[1][t + 256] + s_part[2][t + 256] + s_part[3][t + 256];
  atomicAdd(&y[mb * H_ + t], v0);
  atomicAdd(&y[mb * H_ + t + 256], v1);
}

// ---------------- K4: go[b][k] += coef_mod * tanh(y[mb]^T W_mod + b_mod[0]) ----------------
__global__ __launch_bounds__(256) void k_go(const float* __restrict__ y,
                                            const float* __restrict__ Wtt, const float* __restrict__ btt,
                                            const float* __restrict__ Wit, const float* __restrict__ bit,
                                            float* __restrict__ go) {
  int bid = blockIdx.x;          // 0..127: (half, mb)
  int mb = bid & 63, half = bid >> 6;
  int b = mb & 31, mod = mb >> 5;
  const float* W = mod ? Wit : Wtt;
  const float* bias = mod ? bit : btt;
  float coef = mod ? 0.3f : 0.7f;
  const float* yy = y + mb * H_;
  int k = half * 256 + threadIdx.x;
  float a = bias[k];
  #pragma unroll 8
  for (int h = 0; h < H_; ++h) a = fmaf(yy[h], W[h * H_ + k], a);
  atomicAdd(&go[b * H_ + k], coef * tanh_fast(a));
}

// ---------------- K5: out = 0.5*(nrm*qs*q) + 0.5*graph_o; XCD-pinned mb mapping ----------------
__global__ __launch_bounds__(256) void k_out(const signed char* __restrict__ xq,
                                             const float* __restrict__ nrm, const float* __restrict__ qs,
                                             const float* __restrict__ go, float* __restrict__ out) {
  int u = blockIdx.x;                       // [0,16000)
  int w = threadIdx.x >> 6, lane = threadIdx.x & 63;
  int xcd = u & 7, v = u >> 3;              // v in [0,2000)
  int mbix = v / 250;                       // [0,8)
  int rowgrp = v - mbix * 250;              // [0,250)
  int mb = mbix * 8 + xcd;                  // mb&7 == blockIdx%8
  int mod = mb >> 5, b = mb & 31;
  int c = rowgrp * 4 + w;                   // [0,1000)
  size_t node_off = (size_t)(mb * NP + c + 1);
  float hnq = 0.5f * nrm[node_off] * qs[node_off];
  uint2 x = *(const uint2*)(xq + node_off * H_ + lane * 8);
  const float4* g4 = (const float4*)(go + b * H_ + lane * 8);
  float4 g0 = g4[0], g1 = g4[1];
  float4 o0, o1;
  o0.x = fmaf(hnq, sc2f(x.x), 0.5f * g0.x);
  o0.y = fmaf(hnq, sc2f(x.x >> 8), 0.5f * g0.y);
  o0.z = fmaf(hnq, sc2f(x.x >> 16), 0.5f * g0.z);
  o0.w = fmaf(hnq, sc2f(x.x >> 24), 0.5f * g0.w);
  o1.x = fmaf(hnq, sc2f(x.y), 0.5f * g1.x);
  o1.y = fmaf(hnq, sc2f(x.y >> 8), 0.5f * g1.y);
  o1.z = fmaf(hnq, sc2f(x.y >> 16), 0.5f * g1.z);
  o1.w = fmaf(hnq, sc2f(x.y >> 24), 0.5f * g1.w);
  size_t orow = (size_t)(mod * 32000 + b * 1000 + c);
  float4* o4 = (float4*)(out + orow * H_ + lane * 8);
  o4[0] = o0; o4[1] = o1;
}

extern "C" void kernel_launch(void* const* d_in, const int* in_sizes, int n_in,
                              void* d_out, int out_size, void* d_ws, size_t ws_size,
                              hipStream_t stream) {
  const float* it  = (const float*)d_in[0];
  const float* ii  = (const float*)d_in[1];
  const float* bt  = (const float*)d_in[2];
  const float* bi  = (const float*)d_in[3];
  const float* Wtt = (const float*)d_in[4];
  const float* btt = (const float*)d_in[5];
  const float* Wit = (const float*)d_in[6];
  const float* bit = (const float*)d_in[7];

  char* ws = (char*)d_ws;
  signed char* xq = (signed char*)ws;                             // 2*32*1024*512 i8 = 33,554,432 B
  size_t off = 33554432;
  float* nrm = (float*)(ws + off); off += 262144;                 // [2][32][1024] f32
  float* qs  = (float*)(ws + off); off += 262144;
  float* sc  = (float*)(ws + off); off += 262144;
  float* r   = (float*)(ws + off); off += 262144;                 // zeroed in k_norm
  float* y   = (float*)(ws + off); off += 131072;                 // zeroed in k_norm
  float* go  = (float*)(ws + off); off += 65536;                  // zeroed in k_norm

  k_norm<<<16384, 256, 0, stream>>>(it, ii, bt, bi, xq, nrm, qs, r /* r,y,go contiguous */);
  k_gram<<<64 * 36, 256, 0, stream>>>(xq, qs, r, sc);
  k_y<<<512, 256, 0, stream>>>(xq, r, sc, nrm, qs, y);
  k_go<<<128, 256, 0, stream>>>(y, Wtt, btt, Wit, bit, go);
  k_out<<<16000, 256, 0, stream>>>(xq, nrm, qs, go, (float*)d_out);
}